// Round 3
// baseline (1336.030 us; speedup 1.0000x reference)
//
#include <hip/hip_runtime.h>
#include <hip/hip_bf16.h>

#define N_NODESC 50000
#define N_EDGESC 1600000
#define SDIM 64
#define VDIM 32
#define HID 96
#define IN_DIMC 163
#define NTILES (N_EDGESC / 16)

typedef float f32x4 __attribute__((ext_vector_type(4)));
typedef short s16x8 __attribute__((ext_vector_type(8)));

__device__ __forceinline__ float bf2f(__hip_bfloat16 x) { return __bfloat162float(x); }
__device__ __forceinline__ __hip_bfloat16 f2bf(float x) { return __float2bfloat16(x); }

__device__ __forceinline__ short f2bfbits(float x) {
    union { __hip_bfloat16 h; short s; } u;
    u.h = __float2bfloat16(x);
    return u.s;
}
__device__ __forceinline__ float bfs2f(short s) {
    return __uint_as_float(((unsigned)(unsigned short)s) << 16);
}

// ---------------------------------------------------------------------------
// Detect whether edge_index arrived as int64 (odd int32 words all zero) or int32.
__global__ void detect_kernel(const int* __restrict__ ei, int* __restrict__ flag) {
    int t = threadIdx.x;
    int v = (ei[2 * t + 1] == 0) ? 1 : 0;
    unsigned long long b = __ballot(v);
    if (t == 0) *flag = (b == 0xFFFFFFFFFFFFFFFFULL) ? 1 : 0;
}

// ---------------------------------------------------------------------------
__global__ void init_out(const float* __restrict__ hs, const float* __restrict__ hv,
                         float* __restrict__ out) {
    int i = blockIdx.x * blockDim.x + threadIdx.x;
    if (i >= N_NODESC * (SDIM + VDIM)) return;
    out[i] = (i < N_NODESC * SDIM) ? hs[i] : hv[i - N_NODESC * SDIM];
}

// ---------------------------------------------------------------------------
__global__ void zero_cnt(int* __restrict__ cnt) {
    int i = blockIdx.x * blockDim.x + threadIdx.x;
    if (i < N_NODESC) cnt[i] = 0;
}

// Histogram of src.
__global__ void hist_kernel(const int* __restrict__ ei, const int* __restrict__ flag,
                            int* __restrict__ cnt) {
    const bool i64 = (*flag != 0);
    const long long* e64 = (const long long*)ei;
    for (int e = blockIdx.x * blockDim.x + threadIdx.x; e < N_EDGESC;
         e += gridDim.x * blockDim.x) {
        int s = i64 ? (int)e64[e] : ei[e];
        atomicAdd(&cnt[s], 1);
    }
}

// In-place exclusive scan over 50k bins (cnt -> cursor). One block, 1024 threads.
__global__ __launch_bounds__(1024) void scan_kernel(int* __restrict__ cnt) {
    __shared__ int sums[1024];
    const int t = threadIdx.x;
    const int per = (N_NODESC + 1023) / 1024;  // 49
    const int base = t * per;
    int local = 0;
    int c[49];
    for (int i = 0; i < per; ++i) {
        int idx = base + i;
        c[i] = (idx < N_NODESC) ? cnt[idx] : 0;
        local += c[i];
    }
    sums[t] = local;
    __syncthreads();
    for (int off = 1; off < 1024; off <<= 1) {
        int v = (t >= off) ? sums[t - off] : 0;
        __syncthreads();
        sums[t] += v;
        __syncthreads();
    }
    int run = sums[t] - local;  // exclusive prefix
    for (int i = 0; i < per; ++i) {
        int idx = base + i;
        if (idx < N_NODESC) { cnt[idx] = run; run += c[i]; }
    }
}

// Scatter edges into src-sorted order as packed (src,dst) pairs.
__global__ void scatter_kernel(const int* __restrict__ ei, const int* __restrict__ flag,
                               int* __restrict__ cursor, int2* __restrict__ sorted) {
    const bool i64 = (*flag != 0);
    const long long* e64 = (const long long*)ei;
    for (int e = blockIdx.x * blockDim.x + threadIdx.x; e < N_EDGESC;
         e += gridDim.x * blockDim.x) {
        int s = i64 ? (int)e64[e] : ei[e];
        int d = i64 ? (int)e64[N_EDGESC + e] : ei[N_EDGESC + e];
        int p = atomicAdd(&cursor[s], 1);
        sorted[p] = make_int2(s, d);
    }
}

// ---------------------------------------------------------------------------
// Per-node tables, 8 nodes/block with register reuse of W1.
// T1[n][3][96] = {P, U, V} (src-indexed); T2[n][96] = Q (dst-indexed).
__global__ __launch_bounds__(192) void node_precompute(
    const float* __restrict__ hs, const float* __restrict__ hv,
    const float* __restrict__ W1, const float* __restrict__ b1,
    __hip_bfloat16* __restrict__ T1, __hip_bfloat16* __restrict__ T2) {
    __shared__ float s_x[8][96];
    const int b = blockIdx.x, t = threadIdx.x;
    const int base = b * 8;
    for (int i = t; i < 8 * 96; i += 192) {
        int p = i / 96, c = i - p * 96;
        s_x[p][c] = (c < 64) ? hs[(base + p) * 64 + c] : hv[(base + p) * 32 + (c - 64)];
    }
    __syncthreads();
    const int j = t % 96;
    const int half = t / 96;
    float pr_[4], qr[4], ur[4], vr[4];
    float bj = b1[j];
    #pragma unroll
    for (int i = 0; i < 4; ++i) { pr_[i] = bj; qr[i] = 0.f; ur[i] = 0.f; vr[i] = 0.f; }
    for (int k = 0; k < 64; ++k) {
        float wp = W1[k * HID + j];
        float wq = W1[(64 + k) * HID + j];
        #pragma unroll
        for (int i = 0; i < 4; ++i) {
            float x = s_x[half * 4 + i][k];
            pr_[i] += x * wp;
            qr[i] += x * wq;
        }
    }
    for (int pr = 0; pr < 16; ++pr) {
        float wa = W1[(128 + 2 * pr) * HID + j];
        float wb = W1[(129 + 2 * pr) * HID + j];
        #pragma unroll
        for (int i = 0; i < 4; ++i) {
            float x = s_x[half * 4 + i][64 + 2 * pr];
            float y = s_x[half * 4 + i][65 + 2 * pr];
            ur[i] += x * wa + y * wb;
            vr[i] += x * wb - y * wa;
        }
    }
    #pragma unroll
    for (int i = 0; i < 4; ++i) {
        int n = base + half * 4 + i;
        T1[n * 288 + j]       = f2bf(pr_[i]);
        T1[n * 288 + 96 + j]  = f2bf(ur[i]);
        T1[n * 288 + 192 + j] = f2bf(vr[i]);
        T2[n * 96 + j]        = f2bf(qr[i]);
    }
}

// ---------------------------------------------------------------------------
// Main edge kernel over SRC-SORTED edges. One wave owns a 16-edge tile.
__global__ __launch_bounds__(256, 8) void edge_kernel_sorted(
    const int2* __restrict__ sorted, const float* __restrict__ pos,
    const float* __restrict__ ori, const float* __restrict__ W1,
    const float* __restrict__ W2, const float* __restrict__ b2,
    const __hip_bfloat16* __restrict__ T1, const __hip_bfloat16* __restrict__ T2,
    float* __restrict__ out) {
    __shared__ short sW2[18 * 64 * 8];  // W2 B-frags: [nt*3+kt][lane][8]
    __shared__ short sGW[36 * 8];       // geo-weight frags

    const int t = threadIdx.x;
    const int lane = t & 63;
    const int w = t >> 6;
    const int m16 = lane & 15;
    const int q = lane >> 4;

    for (int sI = t; sI < 18 * 64; sI += 256) {
        int f = sI >> 6, l = sI & 63;
        int n = (f / 3) * 16 + (l & 15);
        int k0 = (f % 3) * 32 + (l >> 4) * 8;
        s16x8 v;
        #pragma unroll
        for (int i = 0; i < 8; ++i) v[i] = f2bfbits(W2[(k0 + i) * HID + n]);
        *(s16x8*)&sW2[sI * 8] = v;
    }
    for (int sI = t; sI < 36; sI += 256) {
        int kt = sI / 12, rr = (sI % 12) / 4, qq = sI % 4;
        #pragma unroll
        for (int i = 0; i < 8; ++i)
            sGW[sI * 8 + i] = f2bfbits(W1[(160 + rr) * HID + kt * 32 + qq * 8 + i]);
    }
    __syncthreads();

    float b2v[6];
    #pragma unroll
    for (int nt = 0; nt < 6; ++nt) b2v[nt] = b2[nt * 16 + m16];

    for (int tile = blockIdx.x * 4 + w; tile < NTILES; tile += gridDim.x * 4) {
        int2 se = sorted[tile * 16 + m16];
        const int sN = se.x, dN = se.y;

        float ca, sa, cb, sb;
        __sincosf(2.0f * ori[dN], &sa, &ca);
        __sincosf(2.0f * ori[sN], &sb, &cb);
        float c = cb * ca + sb * sa;
        float s = sb * ca - cb * sa;
        float2 ps = *(const float2*)&pos[2 * sN];
        float2 pd = *(const float2*)&pos[2 * dN];
        float dx = ps.x - pd.x, dy = ps.y - pd.y;
        float d2 = dx * dx + dy * dy;
        float d = sqrtf(d2) + 1e-6f;
        float c2f = 1.0f, s2f = 0.0f;
        if (d2 > 0.f) {
            float inv = 1.0f / d2;
            c2f = (dx * dx - dy * dy) * inv;
            s2f = 2.0f * dx * dy * inv;
        }
        float cg = c2f * ca + s2f * sa;
        float sg = s2f * ca - c2f * sa;

        const s16x8* t1s = (const s16x8*)&T1[sN * 288];
        s16x8 afr[3];
        #pragma unroll
        for (int kt = 0; kt < 3; ++kt) {
            int jv = kt * 4 + q;
            s16x8 Pv = t1s[jv];
            s16x8 Uv = t1s[12 + jv];
            s16x8 Vv = t1s[24 + jv];
            s16x8 Qv = *(const s16x8*)&T2[dN * 96 + kt * 32 + q * 8];
            s16x8 w0 = *(const s16x8*)&sGW[(kt * 12 + q) * 8];
            s16x8 w1r = *(const s16x8*)&sGW[(kt * 12 + 4 + q) * 8];
            s16x8 w2r = *(const s16x8*)&sGW[(kt * 12 + 8 + q) * 8];
            s16x8 hv8;
            #pragma unroll
            for (int i = 0; i < 8; ++i) {
                float pre = bfs2f(Pv[i]) + bfs2f(Qv[i])
                          + c * bfs2f(Uv[i]) + s * bfs2f(Vv[i])
                          + d * bfs2f(w0[i]) + cg * bfs2f(w1r[i]) + sg * bfs2f(w2r[i]);
                float h = pre * __builtin_amdgcn_rcpf(1.0f + __expf(-pre));
                hv8[i] = f2bfbits(h);
            }
            afr[kt] = hv8;
        }

        f32x4 acc[6];
        #pragma unroll
        for (int nt = 0; nt < 6; ++nt) acc[nt] = (f32x4){0.f, 0.f, 0.f, 0.f};
        #pragma unroll
        for (int nt = 0; nt < 6; ++nt)
            #pragma unroll
            for (int kt = 0; kt < 3; ++kt) {
                s16x8 bf = *(const s16x8*)&sW2[((nt * 3 + kt) * 64 + lane) * 8];
                acc[nt] = __builtin_amdgcn_mfma_f32_16x16x32_bf16(afr[kt], bf, acc[nt], 0, 0, 0);
            }

        int dsts[4];
        #pragma unroll
        for (int r = 0; r < 4; ++r) dsts[r] = __shfl(dN, q * 4 + r, 64);
        #pragma unroll
        for (int nt = 0; nt < 6; ++nt) {
            int u = nt * 16 + m16;
            #pragma unroll
            for (int r = 0; r < 4; ++r) {
                float val = acc[nt][r] + b2v[nt];
                if (nt < 4) atomicAdd(&out[dsts[r] * SDIM + u], val);
                else atomicAdd(&out[N_NODESC * SDIM + dsts[r] * VDIM + (u - SDIM)], val);
            }
        }
    }
}

// ---------------------------------------------------------------------------
// Mid tier: unsorted gather kernel (round-2 behavior) if ws can't fit the sort.
__global__ __launch_bounds__(256, 4) void edge_kernel_gather(
    const int* __restrict__ ei, const float* __restrict__ pos,
    const float* __restrict__ ori, const float* __restrict__ W1,
    const float* __restrict__ W2, const float* __restrict__ b2,
    const __hip_bfloat16* __restrict__ T1, const __hip_bfloat16* __restrict__ T2,
    const int* __restrict__ flag64, float* __restrict__ out) {
    __shared__ short sW2[18 * 64 * 8];
    __shared__ short sGW[36 * 8];

    const int t = threadIdx.x;
    const int lane = t & 63;
    const int w = t >> 6;
    const int m16 = lane & 15;
    const int q = lane >> 4;

    for (int sI = t; sI < 18 * 64; sI += 256) {
        int f = sI >> 6, l = sI & 63;
        int n = (f / 3) * 16 + (l & 15);
        int k0 = (f % 3) * 32 + (l >> 4) * 8;
        s16x8 v;
        #pragma unroll
        for (int i = 0; i < 8; ++i) v[i] = f2bfbits(W2[(k0 + i) * HID + n]);
        *(s16x8*)&sW2[sI * 8] = v;
    }
    for (int sI = t; sI < 36; sI += 256) {
        int kt = sI / 12, rr = (sI % 12) / 4, qq = sI % 4;
        #pragma unroll
        for (int i = 0; i < 8; ++i)
            sGW[sI * 8 + i] = f2bfbits(W1[(160 + rr) * HID + kt * 32 + qq * 8 + i]);
    }
    __syncthreads();

    float b2v[6];
    #pragma unroll
    for (int nt = 0; nt < 6; ++nt) b2v[nt] = b2[nt * 16 + m16];

    const bool i64 = (*flag64 != 0);
    const long long* ei64 = (const long long*)ei;

    for (int tile = blockIdx.x * 4 + w; tile < NTILES; tile += gridDim.x * 4) {
        const int e = tile * 16 + m16;
        int sN, dN;
        if (i64) { sN = (int)ei64[e]; dN = (int)ei64[N_EDGESC + e]; }
        else     { sN = ei[e];        dN = ei[N_EDGESC + e]; }

        float ca, sa, cb, sb;
        __sincosf(2.0f * ori[dN], &sa, &ca);
        __sincosf(2.0f * ori[sN], &sb, &cb);
        float c = cb * ca + sb * sa;
        float s = sb * ca - cb * sa;
        float2 ps = *(const float2*)&pos[2 * sN];
        float2 pd = *(const float2*)&pos[2 * dN];
        float dx = ps.x - pd.x, dy = ps.y - pd.y;
        float d2 = dx * dx + dy * dy;
        float d = sqrtf(d2) + 1e-6f;
        float c2f = 1.0f, s2f = 0.0f;
        if (d2 > 0.f) {
            float inv = 1.0f / d2;
            c2f = (dx * dx - dy * dy) * inv;
            s2f = 2.0f * dx * dy * inv;
        }
        float cg = c2f * ca + s2f * sa;
        float sg = s2f * ca - c2f * sa;

        const s16x8* t1s = (const s16x8*)&T1[sN * 288];
        s16x8 afr[3];
        #pragma unroll
        for (int kt = 0; kt < 3; ++kt) {
            int jv = kt * 4 + q;
            s16x8 Pv = t1s[jv];
            s16x8 Uv = t1s[12 + jv];
            s16x8 Vv = t1s[24 + jv];
            s16x8 Qv = *(const s16x8*)&T2[dN * 96 + kt * 32 + q * 8];
            s16x8 w0 = *(const s16x8*)&sGW[(kt * 12 + q) * 8];
            s16x8 w1r = *(const s16x8*)&sGW[(kt * 12 + 4 + q) * 8];
            s16x8 w2r = *(const s16x8*)&sGW[(kt * 12 + 8 + q) * 8];
            s16x8 hv8;
            #pragma unroll
            for (int i = 0; i < 8; ++i) {
                float pre = bfs2f(Pv[i]) + bfs2f(Qv[i])
                          + c * bfs2f(Uv[i]) + s * bfs2f(Vv[i])
                          + d * bfs2f(w0[i]) + cg * bfs2f(w1r[i]) + sg * bfs2f(w2r[i]);
                float h = pre * __builtin_amdgcn_rcpf(1.0f + __expf(-pre));
                hv8[i] = f2bfbits(h);
            }
            afr[kt] = hv8;
        }

        f32x4 acc[6];
        #pragma unroll
        for (int nt = 0; nt < 6; ++nt) acc[nt] = (f32x4){0.f, 0.f, 0.f, 0.f};
        #pragma unroll
        for (int nt = 0; nt < 6; ++nt)
            #pragma unroll
            for (int kt = 0; kt < 3; ++kt) {
                s16x8 bf = *(const s16x8*)&sW2[((nt * 3 + kt) * 64 + lane) * 8];
                acc[nt] = __builtin_amdgcn_mfma_f32_16x16x32_bf16(afr[kt], bf, acc[nt], 0, 0, 0);
            }

        int dsts[4];
        #pragma unroll
        for (int r = 0; r < 4; ++r) dsts[r] = __shfl(dN, q * 4 + r, 64);
        #pragma unroll
        for (int nt = 0; nt < 6; ++nt) {
            int u = nt * 16 + m16;
            #pragma unroll
            for (int r = 0; r < 4; ++r) {
                float val = acc[nt][r] + b2v[nt];
                if (nt < 4) atomicAdd(&out[dsts[r] * SDIM + u], val);
                else atomicAdd(&out[N_NODESC * SDIM + dsts[r] * VDIM + (u - SDIM)], val);
            }
        }
    }
}

// ---------------------------------------------------------------------------
// Fallback (tiny ws): fully per-edge, correct but slow.
__global__ __launch_bounds__(192) void edge_fallback(
    const int* __restrict__ ei, const float* __restrict__ hs,
    const float* __restrict__ hv, const float* __restrict__ pos,
    const float* __restrict__ ori, const float* __restrict__ W1,
    const float* __restrict__ b1, const float* __restrict__ W2,
    const float* __restrict__ b2, const int* __restrict__ flag64,
    float* __restrict__ out) {
    __shared__ float s_msg[IN_DIMC];
    __shared__ float s_h[HID];
    int e = blockIdx.x;
    int t = threadIdx.x;
    const bool i64 = (*flag64 != 0);
    int sN, dN;
    if (i64) {
        const long long* e64 = (const long long*)ei;
        sN = (int)e64[e]; dN = (int)e64[N_EDGESC + e];
    } else { sN = ei[e]; dN = ei[N_EDGESC + e]; }

    if (t < IN_DIMC) {
        if (t < 64) s_msg[t] = hs[sN * SDIM + t];
        else if (t < 128) s_msg[t] = hs[dN * SDIM + (t - 64)];
        else {
            float ca, sa, cb, sb;
            __sincosf(2.0f * ori[dN], &sa, &ca);
            __sincosf(2.0f * ori[sN], &sb, &cb);
            float c = cb * ca + sb * sa;
            float s = sb * ca - cb * sa;
            float dx = pos[2 * sN] - pos[2 * dN];
            float dy = pos[2 * sN + 1] - pos[2 * dN + 1];
            float d2 = dx * dx + dy * dy;
            if (t < 160) {
                int pr = (t - 128) >> 1;
                float x = hv[sN * VDIM + 2 * pr], y = hv[sN * VDIM + 2 * pr + 1];
                s_msg[t] = ((t & 1) == 0) ? (c * x - s * y) : (s * x + c * y);
            } else if (t == 160) s_msg[t] = sqrtf(d2) + 1e-6f;
            else {
                float c2f = 1.0f, s2f = 0.0f;
                if (d2 > 0.f) {
                    float inv = 1.0f / d2;
                    c2f = (dx * dx - dy * dy) * inv;
                    s2f = 2.0f * dx * dy * inv;
                }
                s_msg[t] = (t == 161) ? (c2f * ca + s2f * sa) : (s2f * ca - c2f * sa);
            }
        }
    }
    __syncthreads();
    if (t < HID) {
        float a = b1[t];
        for (int k = 0; k < IN_DIMC; ++k) a += s_msg[k] * W1[k * HID + t];
        s_h[t] = a / (1.0f + __expf(-a));
    }
    __syncthreads();
    if (t < HID) {
        float a = b2[t];
        for (int k = 0; k < HID; ++k) a += s_h[k] * W2[k * HID + t];
        if (t < SDIM) atomicAdd(&out[dN * SDIM + t], a);
        else atomicAdd(&out[N_NODESC * SDIM + dN * VDIM + (t - SDIM)], a);
    }
}

// ---------------------------------------------------------------------------
extern "C" void kernel_launch(void* const* d_in, const int* in_sizes, int n_in,
                              void* d_out, int out_size, void* d_ws, size_t ws_size,
                              hipStream_t stream) {
    const float* hs  = (const float*)d_in[0];
    const float* hv  = (const float*)d_in[1];
    const int*   ei  = (const int*)d_in[2];
    const float* pos = (const float*)d_in[3];
    const float* ori = (const float*)d_in[4];
    const float* W1  = (const float*)d_in[5];
    const float* b1  = (const float*)d_in[6];
    const float* W2  = (const float*)d_in[7];
    const float* b2  = (const float*)d_in[8];
    float* out = (float*)d_out;

    const size_t T1B   = (size_t)N_NODESC * 288 * sizeof(__hip_bfloat16);  // 28.8 MB
    const size_t T2B   = (size_t)N_NODESC * 96 * sizeof(__hip_bfloat16);   //  9.6 MB
    const size_t SORTB = (size_t)N_EDGESC * sizeof(int2);                  // 12.8 MB
    const size_t CNTB  = (size_t)N_NODESC * sizeof(int);                   //  0.2 MB
    const size_t FULL  = T1B + T2B + SORTB + CNTB + 64;
    const size_t MID   = T1B + T2B + 64;

    init_out<<<(N_NODESC * (SDIM + VDIM) + 255) / 256, 256, 0, stream>>>(hs, hv, out);

    if (ws_size >= FULL) {
        char* ws = (char*)d_ws;
        __hip_bfloat16* T1 = (__hip_bfloat16*)(ws);
        __hip_bfloat16* T2 = (__hip_bfloat16*)(ws + T1B);
        int2* sorted       = (int2*)(ws + T1B + T2B);
        int*  cnt          = (int*)(ws + T1B + T2B + SORTB);
        int*  flag         = (int*)(ws + T1B + T2B + SORTB + CNTB);

        detect_kernel<<<1, 64, 0, stream>>>(ei, flag);
        zero_cnt<<<(N_NODESC + 255) / 256, 256, 0, stream>>>(cnt);
        hist_kernel<<<512, 256, 0, stream>>>(ei, flag, cnt);
        scan_kernel<<<1, 1024, 0, stream>>>(cnt);
        scatter_kernel<<<512, 256, 0, stream>>>(ei, flag, cnt, sorted);
        node_precompute<<<N_NODESC / 8, 192, 0, stream>>>(hs, hv, W1, b1, T1, T2);
        edge_kernel_sorted<<<2048, 256, 0, stream>>>(sorted, pos, ori, W1, W2, b2,
                                                     T1, T2, out);
    } else if (ws_size >= MID) {
        char* ws = (char*)d_ws;
        __hip_bfloat16* T1 = (__hip_bfloat16*)(ws);
        __hip_bfloat16* T2 = (__hip_bfloat16*)(ws + T1B);
        int* flag = (int*)(ws + T1B + T2B);
        detect_kernel<<<1, 64, 0, stream>>>(ei, flag);
        node_precompute<<<N_NODESC / 8, 192, 0, stream>>>(hs, hv, W1, b1, T1, T2);
        edge_kernel_gather<<<2500, 256, 0, stream>>>(ei, pos, ori, W1, W2, b2,
                                                     T1, T2, flag, out);
    } else {
        int* flag = (int*)d_ws;
        detect_kernel<<<1, 64, 0, stream>>>(ei, flag);
        edge_fallback<<<N_EDGESC, 192, 0, stream>>>(ei, hs, hv, pos, ori, W1, b1,
                                                    W2, b2, flag, out);
    }
}

// Round 4
// 1160.049 us; speedup vs baseline: 1.1517x; 1.1517x over previous
//
#include <hip/hip_runtime.h>
#include <hip/hip_bf16.h>

#define N_NODESC 50000
#define N_EDGESC 1600000
#define SDIM 64
#define VDIM 32
#define HID 96
#define IN_DIMC 163
#define NTILES (N_EDGESC / 16)
#define NBLK 768

typedef float f32x4 __attribute__((ext_vector_type(4)));
typedef short s16x8 __attribute__((ext_vector_type(8)));

__device__ __forceinline__ __hip_bfloat16 f2bf(float x) { return __float2bfloat16(x); }
__device__ __forceinline__ short f2bfbits(float x) {
    union { __hip_bfloat16 h; short s; } u;
    u.h = __float2bfloat16(x);
    return u.s;
}
__device__ __forceinline__ float bfs2f(short s) {
    return __uint_as_float(((unsigned)(unsigned short)s) << 16);
}

// ---------------------------------------------------------------------------
__global__ void detect_kernel(const int* __restrict__ ei, int* __restrict__ flag) {
    int t = threadIdx.x;
    int v = (ei[2 * t + 1] == 0) ? 1 : 0;
    unsigned long long b = __ballot(v);
    if (t == 0) *flag = (b == 0xFFFFFFFFFFFFFFFFULL) ? 1 : 0;
}

// ---------------------------------------------------------------------------
__global__ void init_out(const float* __restrict__ hs, const float* __restrict__ hv,
                         float* __restrict__ out) {
    int i = blockIdx.x * blockDim.x + threadIdx.x;
    if (i >= N_NODESC * (SDIM + VDIM)) return;
    out[i] = (i < N_NODESC * SDIM) ? hs[i] : hv[i - N_NODESC * SDIM];
}

// ---------------------------------------------------------------------------
// Pack node features as bf16 rows of 128 (256 B, 2 cache lines exactly):
// [hs(64) | hv(32) | zeros(32)]. Zeros are REQUIRED every call (ws poisoned).
__global__ void pack_X(const float* __restrict__ hs, const float* __restrict__ hv,
                       __hip_bfloat16* __restrict__ X) {
    int i = blockIdx.x * blockDim.x + threadIdx.x;
    if (i >= N_NODESC * 128) return;
    int n = i >> 7, j = i & 127;
    float v = (j < 64) ? hs[n * 64 + j] : (j < 96 ? hv[n * 32 + (j - 64)] : 0.f);
    X[i] = f2bf(v);
}

// ---------------------------------------------------------------------------
__global__ void zero_cnt(int* __restrict__ cnt) {
    int i = blockIdx.x * blockDim.x + threadIdx.x;
    if (i < N_NODESC) cnt[i] = 0;
}

// Histogram of DST.
__global__ void hist_kernel(const int* __restrict__ ei, const int* __restrict__ flag,
                            int* __restrict__ cnt) {
    const bool i64 = (*flag != 0);
    const long long* e64 = (const long long*)ei;
    for (int e = blockIdx.x * blockDim.x + threadIdx.x; e < N_EDGESC;
         e += gridDim.x * blockDim.x) {
        int d = i64 ? (int)e64[N_EDGESC + e] : ei[N_EDGESC + e];
        atomicAdd(&cnt[d], 1);
    }
}

// In-place exclusive scan over 50k bins. One block.
__global__ __launch_bounds__(1024) void scan_kernel(int* __restrict__ cnt) {
    __shared__ int sums[1024];
    const int t = threadIdx.x;
    const int per = (N_NODESC + 1023) / 1024;  // 49
    const int base = t * per;
    int local = 0;
    int c[49];
    for (int i = 0; i < per; ++i) {
        int idx = base + i;
        c[i] = (idx < N_NODESC) ? cnt[idx] : 0;
        local += c[i];
    }
    sums[t] = local;
    __syncthreads();
    for (int off = 1; off < 1024; off <<= 1) {
        int v = (t >= off) ? sums[t - off] : 0;
        __syncthreads();
        sums[t] += v;
        __syncthreads();
    }
    int run = sums[t] - local;
    for (int i = 0; i < per; ++i) {
        int idx = base + i;
        if (idx < N_NODESC) { cnt[idx] = run; run += c[i]; }
    }
}

// Scatter edges into DST-sorted order as packed (src,dst) pairs.
__global__ void scatter_kernel(const int* __restrict__ ei, const int* __restrict__ flag,
                               int* __restrict__ cursor, int2* __restrict__ sorted) {
    const bool i64 = (*flag != 0);
    const long long* e64 = (const long long*)ei;
    for (int e = blockIdx.x * blockDim.x + threadIdx.x; e < N_EDGESC;
         e += gridDim.x * blockDim.x) {
        int s = i64 ? (int)e64[e] : ei[e];
        int d = i64 ? (int)e64[N_EDGESC + e] : ei[N_EDGESC + e];
        int p = atomicAdd(&cursor[d], 1);
        sorted[p] = make_int2(s, d);
    }
}

// ---------------------------------------------------------------------------
// Main edge kernel over DST-SORTED edges. One wave owns a 16-edge tile.
// Layer 1: full K=192 MFMA GEMM, A assembled in-register from X rows
// (src random = 2 lines; dst tile-uniform = cached) + in-register rotation +
// geo slots. B = W1 rows 0..162 as LDS frags (fixed). Layer 2: W2 frags in
// VGPRs. Epilogue: run-merged atomics (dst-sorted rows).
__global__ __launch_bounds__(256, 3) void edge_kernel_v4(
    const int2* __restrict__ sorted, const float* __restrict__ pos,
    const float* __restrict__ ori, const float* __restrict__ W1,
    const float* __restrict__ W2, const float* __restrict__ b1,
    const float* __restrict__ b2, const __hip_bfloat16* __restrict__ X,
    float* __restrict__ out) {
    __shared__ short sW1[36 * 64 * 8];   // L1 B-frags: [(nt*6+kt)][lane][8] (36 KB)
    __shared__ short sHA[4][16 * 104];   // per-wave h scratch, pitch 104 sh (13 KB)

    const int t = threadIdx.x;
    const int lane = t & 63;
    const int w = t >> 6;
    const int m16 = lane & 15;
    const int q = lane >> 4;

    // Stage W1 B-frags: frag(kt,nt) lane holds B[k=kt*32+q*8+i][n=nt*16+m16],
    // rows >= 163 are zero.
    for (int sI = t; sI < 36 * 64; sI += 256) {
        int f = sI >> 6, l = sI & 63;
        int kt = f % 6, nt = f / 6;
        int n = nt * 16 + (l & 15);
        int k0 = kt * 32 + (l >> 4) * 8;
        s16x8 v;
        #pragma unroll
        for (int i = 0; i < 8; ++i) {
            int k = k0 + i;
            v[i] = (k < IN_DIMC) ? f2bfbits(W1[k * HID + n]) : (short)0;
        }
        *(s16x8*)&sW1[sI * 8] = v;
    }
    __syncthreads();

    // W2 B-frags direct from global into VGPRs (W2 is L2-hot, one-time).
    s16x8 bfr[6][3];
    #pragma unroll
    for (int nt = 0; nt < 6; ++nt)
        #pragma unroll
        for (int kt = 0; kt < 3; ++kt) {
            int n = nt * 16 + m16;
            int k0 = kt * 32 + q * 8;
            s16x8 v;
            #pragma unroll
            for (int i = 0; i < 8; ++i) v[i] = f2bfbits(W2[(k0 + i) * HID + n]);
            bfr[nt][kt] = v;
        }
    float b1v[6], b2v[6];
    #pragma unroll
    for (int nt = 0; nt < 6; ++nt) {
        b1v[nt] = b1[nt * 16 + m16];
        b2v[nt] = b2[nt * 16 + m16];
    }

    // XCD-chunked tile range: block b serves XCD b&7's contiguous chunk.
    const int CHUNK = NTILES / 8;                 // 12500
    const int tbeg = (blockIdx.x & 7) * CHUNK;
    const int tend = tbeg + CHUNK;
    const int STRIDE = (NBLK / 8) * 4;            // 384

    int tile0 = tbeg + (blockIdx.x >> 3) * 4 + w;
    int2 se;
    if (tile0 < tend) se = sorted[tile0 * 16 + m16];

    for (int tile = tile0; tile < tend; tile += STRIDE) {
        int nextTile = tile + STRIDE;
        int2 seN;
        if (nextTile < tend) seN = sorted[nextTile * 16 + m16];

        const int sN = se.x, dN = se.y;
        const __hip_bfloat16* Xs = X + (size_t)sN * 128;
        const __hip_bfloat16* Xd = X + (size_t)dN * 128;

        // Issue feature loads early.
        s16x8 a0 = *(const s16x8*)&Xs[q * 8];          // hs_src lo
        s16x8 a1 = *(const s16x8*)&Xs[32 + q * 8];     // hs_src hi
        s16x8 a2 = *(const s16x8*)&Xd[q * 8];          // hs_dst lo
        s16x8 a3 = *(const s16x8*)&Xd[32 + q * 8];     // hs_dst hi
        s16x8 av = *(const s16x8*)&Xs[64 + q * 8];     // hv_src (4 pairs)

        // Geometry (per edge m16, redundantly across q-groups).
        float ca, sa, cb, sb;
        __sincosf(2.0f * ori[dN], &sa, &ca);
        __sincosf(2.0f * ori[sN], &sb, &cb);
        float c = cb * ca + sb * sa;   // cos(2(beta-alpha))
        float s = sb * ca - cb * sa;   // sin(2(beta-alpha))
        float2 ps = *(const float2*)&pos[2 * sN];
        float2 pd = *(const float2*)&pos[2 * dN];
        float dx = ps.x - pd.x, dy = ps.y - pd.y;
        float d2 = dx * dx + dy * dy;
        float d = sqrtf(d2) + 1e-6f;
        float c2f = 1.0f, s2f = 0.0f;
        if (d2 > 0.f) {
            float inv = 1.0f / d2;
            c2f = (dx * dx - dy * dy) * inv;
            s2f = 2.0f * dx * dy * inv;
        }
        float cg = c2f * ca + s2f * sa;  // cos(2phi-2alpha)
        float sg = s2f * ca - c2f * sa;  // sin(2phi-2alpha)

        // Rotate the 4 in-lane (x,y) pairs of hv_src: A slots k=128..159.
        s16x8 a4;
        #pragma unroll
        for (int p = 0; p < 4; ++p) {
            float x = bfs2f(av[2 * p]), y = bfs2f(av[2 * p + 1]);
            a4[2 * p]     = f2bfbits(c * x - s * y);
            a4[2 * p + 1] = f2bfbits(s * x + c * y);
        }
        // Geo slots k=160..162 (only q==0 lanes hold data).
        s16x8 a5 = (s16x8){0, 0, 0, 0, 0, 0, 0, 0};
        if (q == 0) {
            a5[0] = f2bfbits(d);
            a5[1] = f2bfbits(cg);
            a5[2] = f2bfbits(sg);
        }

        // Layer 1 MFMA: 6 kt x 6 nt, B-frags from LDS.
        f32x4 acc1[6];
        #pragma unroll
        for (int nt = 0; nt < 6; ++nt) acc1[nt] = (f32x4){0.f, 0.f, 0.f, 0.f};
        s16x8 afr[6] = {a0, a1, a2, a3, a4, a5};
        #pragma unroll
        for (int kt = 0; kt < 6; ++kt)
            #pragma unroll
            for (int nt = 0; nt < 6; ++nt) {
                s16x8 bf = *(const s16x8*)&sW1[((nt * 6 + kt) * 64 + lane) * 8];
                acc1[nt] = __builtin_amdgcn_mfma_f32_16x16x32_bf16(afr[kt], bf, acc1[nt], 0, 0, 0);
            }

        // silu + write to per-wave LDS scratch in (edge, j) layout.
        // C layout: j = nt*16+m16, edge = q*4+r.
        #pragma unroll
        for (int nt = 0; nt < 6; ++nt) {
            int j = nt * 16 + m16;
            #pragma unroll
            for (int r = 0; r < 4; ++r) {
                float pre = acc1[nt][r] + b1v[nt];
                float h = pre * __builtin_amdgcn_rcpf(1.0f + __expf(-pre));
                sHA[w][(q * 4 + r) * 104 + j] = f2bfbits(h);
            }
        }

        // Layer 2: A-frags from scratch, B-frags in VGPRs.
        s16x8 afr2[3];
        #pragma unroll
        for (int kt = 0; kt < 3; ++kt)
            afr2[kt] = *(const s16x8*)&sHA[w][m16 * 104 + kt * 32 + q * 8];
        f32x4 acc2[6];
        #pragma unroll
        for (int nt = 0; nt < 6; ++nt) acc2[nt] = (f32x4){0.f, 0.f, 0.f, 0.f};
        #pragma unroll
        for (int nt = 0; nt < 6; ++nt)
            #pragma unroll
            for (int kt = 0; kt < 3; ++kt)
                acc2[nt] = __builtin_amdgcn_mfma_f32_16x16x32_bf16(afr2[kt], bfr[nt][kt], acc2[nt], 0, 0, 0);

        // Epilogue: run-merged atomics (rows sorted by dst).
        int dsts[4];
        #pragma unroll
        for (int r = 0; r < 4; ++r) dsts[r] = __shfl(dN, q * 4 + r, 64);
        bool brk0 = (dsts[1] != dsts[0]);
        bool brk1 = (dsts[2] != dsts[1]);
        bool brk2 = (dsts[3] != dsts[2]);
        #pragma unroll
        for (int nt = 0; nt < 6; ++nt) {
            int u = nt * 16 + m16;
            float* basep = (nt < 4) ? &out[(size_t)0 * 1 + u]  // scalar block
                                    : &out[(size_t)N_NODESC * SDIM + (u - SDIM)];
            int rowstride = (nt < 4) ? SDIM : VDIM;
            float run = acc2[nt][0] + b2v[nt];
            if (brk0) { atomicAdd(basep + (size_t)dsts[0] * rowstride, run); run = 0.f; }
            run += acc2[nt][1] + b2v[nt];
            if (brk1) { atomicAdd(basep + (size_t)dsts[1] * rowstride, run); run = 0.f; }
            run += acc2[nt][2] + b2v[nt];
            if (brk2) { atomicAdd(basep + (size_t)dsts[2] * rowstride, run); run = 0.f; }
            run += acc2[nt][3] + b2v[nt];
            atomicAdd(basep + (size_t)dsts[3] * rowstride, run);
        }

        se = seN;
    }
}

// ---------------------------------------------------------------------------
// Fallback (tiny ws): fully per-edge, correct but slow.
__global__ __launch_bounds__(192) void edge_fallback(
    const int* __restrict__ ei, const float* __restrict__ hs,
    const float* __restrict__ hv, const float* __restrict__ pos,
    const float* __restrict__ ori, const float* __restrict__ W1,
    const float* __restrict__ b1, const float* __restrict__ W2,
    const float* __restrict__ b2, const int* __restrict__ flag64,
    float* __restrict__ out) {
    __shared__ float s_msg[IN_DIMC];
    __shared__ float s_h[HID];
    int e = blockIdx.x;
    int t = threadIdx.x;
    const bool i64 = (*flag64 != 0);
    int sN, dN;
    if (i64) {
        const long long* e64 = (const long long*)ei;
        sN = (int)e64[e]; dN = (int)e64[N_EDGESC + e];
    } else { sN = ei[e]; dN = ei[N_EDGESC + e]; }

    if (t < IN_DIMC) {
        if (t < 64) s_msg[t] = hs[sN * SDIM + t];
        else if (t < 128) s_msg[t] = hs[dN * SDIM + (t - 64)];
        else {
            float ca, sa, cb, sb;
            __sincosf(2.0f * ori[dN], &sa, &ca);
            __sincosf(2.0f * ori[sN], &sb, &cb);
            float c = cb * ca + sb * sa;
            float s = sb * ca - cb * sa;
            float dx = pos[2 * sN] - pos[2 * dN];
            float dy = pos[2 * sN + 1] - pos[2 * dN + 1];
            float d2 = dx * dx + dy * dy;
            if (t < 160) {
                int pr = (t - 128) >> 1;
                float x = hv[sN * VDIM + 2 * pr], y = hv[sN * VDIM + 2 * pr + 1];
                s_msg[t] = ((t & 1) == 0) ? (c * x - s * y) : (s * x + c * y);
            } else if (t == 160) s_msg[t] = sqrtf(d2) + 1e-6f;
            else {
                float c2f = 1.0f, s2f = 0.0f;
                if (d2 > 0.f) {
                    float inv = 1.0f / d2;
                    c2f = (dx * dx - dy * dy) * inv;
                    s2f = 2.0f * dx * dy * inv;
                }
                s_msg[t] = (t == 161) ? (c2f * ca + s2f * sa) : (s2f * ca - c2f * sa);
            }
        }
    }
    __syncthreads();
    if (t < HID) {
        float a = b1[t];
        for (int k = 0; k < IN_DIMC; ++k) a += s_msg[k] * W1[k * HID + t];
        s_h[t] = a / (1.0f + __expf(-a));
    }
    __syncthreads();
    if (t < HID) {
        float a = b2[t];
        for (int k = 0; k < HID; ++k) a += s_h[k] * W2[k * HID + t];
        if (t < SDIM) atomicAdd(&out[dN * SDIM + t], a);
        else atomicAdd(&out[N_NODESC * SDIM + dN * VDIM + (t - SDIM)], a);
    }
}

// ---------------------------------------------------------------------------
extern "C" void kernel_launch(void* const* d_in, const int* in_sizes, int n_in,
                              void* d_out, int out_size, void* d_ws, size_t ws_size,
                              hipStream_t stream) {
    const float* hs  = (const float*)d_in[0];
    const float* hv  = (const float*)d_in[1];
    const int*   ei  = (const int*)d_in[2];
    const float* pos = (const float*)d_in[3];
    const float* ori = (const float*)d_in[4];
    const float* W1  = (const float*)d_in[5];
    const float* b1  = (const float*)d_in[6];
    const float* W2  = (const float*)d_in[7];
    const float* b2  = (const float*)d_in[8];
    float* out = (float*)d_out;

    const size_t XB    = (size_t)N_NODESC * 128 * sizeof(__hip_bfloat16);  // 12.8 MB
    const size_t SORTB = (size_t)N_EDGESC * sizeof(int2);                  // 12.8 MB
    const size_t CNTB  = (size_t)N_NODESC * sizeof(int);                   //  0.2 MB
    const size_t FULL  = XB + SORTB + CNTB + 64;

    init_out<<<(N_NODESC * (SDIM + VDIM) + 255) / 256, 256, 0, stream>>>(hs, hv, out);

    if (ws_size >= FULL) {
        char* ws = (char*)d_ws;
        __hip_bfloat16* X = (__hip_bfloat16*)(ws);
        int2* sorted      = (int2*)(ws + XB);
        int*  cnt         = (int*)(ws + XB + SORTB);
        int*  flag        = (int*)(ws + XB + SORTB + CNTB);

        detect_kernel<<<1, 64, 0, stream>>>(ei, flag);
        pack_X<<<(N_NODESC * 128 + 255) / 256, 256, 0, stream>>>(hs, hv, X);
        zero_cnt<<<(N_NODESC + 255) / 256, 256, 0, stream>>>(cnt);
        hist_kernel<<<512, 256, 0, stream>>>(ei, flag, cnt);
        scan_kernel<<<1, 1024, 0, stream>>>(cnt);
        scatter_kernel<<<512, 256, 0, stream>>>(ei, flag, cnt, sorted);
        edge_kernel_v4<<<NBLK, 256, 0, stream>>>(sorted, pos, ori, W1, W2, b1, b2,
                                                 X, out);
    } else {
        int* flag = (int*)d_ws;
        detect_kernel<<<1, 64, 0, stream>>>(ei, flag);
        edge_fallback<<<N_EDGESC, 192, 0, stream>>>(ei, hs, hv, pos, ori, W1, b1,
                                                    W2, b2, flag, out);
    }
}